// Round 3
// baseline (328.220 us; speedup 1.0000x reference)
//
#include <hip/hip_runtime.h>
#include <math.h>

#define H        2880
#define H4       720      // H / 4
#define NTOK     16384
#define NEXP     128
#define KT       32       // K chunk
#define NCHUNK   90       // 2880 / 32
#define BM       64       // tokens per block
#define BN       128      // experts per block (all)

// LDS layout (float words): slab per kk4 (4 consecutive k as float4), rows in
// groups of 8 with 4 pad words (36 words/group -> 144B, 16B aligned) so the
// per-group bank start advances by 4 banks: breaks the 4-way read conflict.
#define XSLAB 288         // 8 groups * 36
#define WSLAB 576         // 16 groups * 36

// ---------------- Kernel 1: router GEMM, split-K (fp32 FMA, fp64 chunk cascade) ------------
__global__ __launch_bounds__(256) void router_gemm(
    const float* __restrict__ x,      // [NTOK][H]
    const float* __restrict__ w,      // [NEXP][H]
    float* __restrict__ p0,           // [NTOK][NEXP] partial slice 0
    float* __restrict__ pws)          // [KS-1][NTOK][NEXP] partial slices 1..
{
    __shared__ float xs [8 * XSLAB];  // 9216 B
    __shared__ float wsl[8 * WSLAB];  // 18432 B

    const int tid = threadIdx.x;
    const int bm  = blockIdx.x;       // 0..255 token tile
    const int z   = blockIdx.y;       // k slice
    const int ks  = gridDim.y;
    const int t0  = bm * BM;

    const int tn  = tid & 31;         // expert group: 4 experts
    const int tm  = tid >> 5;         // token group: 8 tokens

    const int base = NCHUNK / ks, rem = NCHUNK % ks;
    const int c0 = z * base + (z < rem ? z : rem);
    const int c1 = c0 + base + (z < rem ? 1 : 0);

    float* outp = (z == 0) ? p0 : (pws + (size_t)(z - 1) * NTOK * NEXP);

    const float4* xg = reinterpret_cast<const float4*>(x);
    const float4* wg = reinterpret_cast<const float4*>(w);

    const int ldrow = tid >> 3;       // 0..31
    const int ldkq  = tid & 7;        // slab

    double acc[8][4];
    float  c32[8][4];
#pragma unroll
    for (int i = 0; i < 8; ++i)
#pragma unroll
        for (int j = 0; j < 4; ++j) { acc[i][j] = 0.0; c32[i][j] = 0.0f; }

    float4 xr0, xr1, wr0, wr1, wr2, wr3;

#define LOAD_CHUNK(c)                                                          \
    {                                                                          \
        const int ko = (c) * 8 + ldkq;                                         \
        xr0 = xg[(size_t)(t0 + ldrow     ) * H4 + ko];                         \
        xr1 = xg[(size_t)(t0 + ldrow + 32) * H4 + ko];                         \
        wr0 = wg[(size_t)(ldrow      ) * H4 + ko];                             \
        wr1 = wg[(size_t)(ldrow + 32 ) * H4 + ko];                             \
        wr2 = wg[(size_t)(ldrow + 64 ) * H4 + ko];                             \
        wr3 = wg[(size_t)(ldrow + 96 ) * H4 + ko];                             \
    }

    // float4 stored as loaded (no transpose): 1 ds_write_b128 per row-slot.
#define STORE_LDS()                                                            \
    {                                                                          \
        const int xb = ldkq * XSLAB;                                           \
        const int wb = ldkq * WSLAB;                                           \
        const int g0 = (ldrow >> 3) * 36 + (ldrow & 7) * 4;                    \
        *reinterpret_cast<float4*>(&xs [xb + g0      ]) = xr0;                 \
        *reinterpret_cast<float4*>(&xs [xb + g0 + 144]) = xr1;                 \
        *reinterpret_cast<float4*>(&wsl[wb + g0      ]) = wr0;                 \
        *reinterpret_cast<float4*>(&wsl[wb + g0 + 144]) = wr1;                 \
        *reinterpret_cast<float4*>(&wsl[wb + g0 + 288]) = wr2;                 \
        *reinterpret_cast<float4*>(&wsl[wb + g0 + 432]) = wr3;                 \
    }

    LOAD_CHUNK(c0);
    STORE_LDS();
    __syncthreads();

    for (int c = c0; c < c1; ++c) {
        if (c + 1 < c1) LOAD_CHUNK(c + 1);   // prefetch next chunk into regs

#pragma unroll
        for (int kk4 = 0; kk4 < 8; ++kk4) {
            // experts e = tn*4+j: word = (e>>3)*36 + (e&7)*4 = (tn>>1)*36 + (tn&1)*16 + j*4
            const float* wp = &wsl[kk4 * WSLAB + (tn >> 1) * 36 + (tn & 1) * 16];
            const float4 b0 = *reinterpret_cast<const float4*>(&wp[0]);
            const float4 b1 = *reinterpret_cast<const float4*>(&wp[4]);
            const float4 b2 = *reinterpret_cast<const float4*>(&wp[8]);
            const float4 b3 = *reinterpret_cast<const float4*>(&wp[12]);
            const float* xp = &xs[kk4 * XSLAB + tm * 36];
#pragma unroll
            for (int i = 0; i < 8; ++i) {
                const float4 a = *reinterpret_cast<const float4*>(&xp[i * 4]);
                c32[i][0] = fmaf(a.w, b0.w, fmaf(a.z, b0.z, fmaf(a.y, b0.y, fmaf(a.x, b0.x, c32[i][0]))));
                c32[i][1] = fmaf(a.w, b1.w, fmaf(a.z, b1.z, fmaf(a.y, b1.y, fmaf(a.x, b1.x, c32[i][1]))));
                c32[i][2] = fmaf(a.w, b2.w, fmaf(a.z, b2.z, fmaf(a.y, b2.y, fmaf(a.x, b2.x, c32[i][2]))));
                c32[i][3] = fmaf(a.w, b3.w, fmaf(a.z, b3.z, fmaf(a.y, b3.y, fmaf(a.x, b3.x, c32[i][3]))));
            }
        }

        // cascade chunk sum into fp64 accumulator (near-exact logits)
#pragma unroll
        for (int i = 0; i < 8; ++i)
#pragma unroll
            for (int j = 0; j < 4; ++j) {
                acc[i][j] += (double)c32[i][j];
                c32[i][j] = 0.0f;
            }

        __syncthreads();
        if (c + 1 < c1) STORE_LDS();
        __syncthreads();
    }

    // epilogue: raw partial write (bias added in kernel 2)
#pragma unroll
    for (int i = 0; i < 8; ++i) {
        float4 o;
        o.x = (float)acc[i][0];
        o.y = (float)acc[i][1];
        o.z = (float)acc[i][2];
        o.w = (float)acc[i][3];
        *reinterpret_cast<float4*>(&outp[(size_t)(t0 + tm * 8 + i) * NEXP + tn * 4]) = o;
    }
}

// ---------------- Kernel 2: fused reduce(+bias) + logits write + top-4 + softmax ------------
// 8 threads per token; each scans 16 experts; 3-stage shfl_xor merge of sorted top-4 lists.
#define INSERT(v, e)                                                           \
    if ((v) > v0)      { v3=v2;i3=i2; v2=v1;i2=i1; v1=v0;i1=i0; v0=(v);i0=(e);}\
    else if ((v) > v1) { v3=v2;i3=i2; v2=v1;i2=i1; v1=(v);i1=(e); }            \
    else if ((v) > v2) { v3=v2;i3=i2; v2=(v);i2=(e); }                         \
    else if ((v) > v3) { v3=(v);i3=(e); }

__global__ __launch_bounds__(256) void reduce_topk_softmax(
    float* __restrict__ p0,             // [NTOK][NEXP] partial 0, overwritten with final logits
    const float* __restrict__ pws,      // [KS-1][NTOK][NEXP]
    const float* __restrict__ bias,     // [NEXP]
    float* __restrict__ vals,           // [NTOK][4]
    float* __restrict__ inds,           // [NTOK][4] (float-valued indices)
    int ks)
{
    const int gt   = blockIdx.x * 256 + threadIdx.x;
    const int tok  = gt >> 3;
    const int part = gt & 7;            // expert range [part*16, part*16+16)

    float4*       row4 = reinterpret_cast<float4*>(p0) + (size_t)tok * 32;
    const float4* b4   = reinterpret_cast<const float4*>(bias);

    float v0 = -3.4e38f, v1 = -3.4e38f, v2 = -3.4e38f, v3 = -3.4e38f;
    int   i0 = 0, i1 = 0, i2 = 0, i3 = 0;

#pragma unroll
    for (int g = 0; g < 4; ++g) {
        const int f4i = part * 4 + g;
        float4 s = row4[f4i];
        for (int zz = 1; zz < ks; ++zz) {
            const float4 pz = reinterpret_cast<const float4*>(
                pws + (size_t)(zz - 1) * NTOK * NEXP)[(size_t)tok * 32 + f4i];
            s.x += pz.x; s.y += pz.y; s.z += pz.z; s.w += pz.w;
        }
        const float4 bb = b4[f4i];
        s.x += bb.x; s.y += bb.y; s.z += bb.z; s.w += bb.w;
        row4[f4i] = s;                  // final logits

        const float qq[4] = {s.x, s.y, s.z, s.w};
#pragma unroll
        for (int j = 0; j < 4; ++j) {
            const float v = qq[j];
            const int   e = f4i * 4 + j;
            INSERT(v, e);
        }
    }

    // merge sorted top-4 lists across the 8 threads of this token.
    // lower expert-range list is incumbent -> strict > keeps earliest index on ties.
#pragma unroll
    for (int m = 1; m <= 4; m <<= 1) {
        float u0 = __shfl_xor(v0, m), u1 = __shfl_xor(v1, m),
              u2 = __shfl_xor(v2, m), u3 = __shfl_xor(v3, m);
        int   j0 = __shfl_xor(i0, m), j1 = __shfl_xor(i1, m),
              j2 = __shfl_xor(i2, m), j3 = __shfl_xor(i3, m);
        if (part & m) {
            // I'm the upper range: other's list is incumbent, insert mine into it
            float t0 = v0, t1 = v1, t2 = v2, t3 = v3;
            int   s0 = i0, s1 = i1, s2 = i2, s3 = i3;
            v0 = u0; v1 = u1; v2 = u2; v3 = u3;
            i0 = j0; i1 = j1; i2 = j2; i3 = j3;
            INSERT(t0, s0); INSERT(t1, s1); INSERT(t2, s2); INSERT(t3, s3);
        } else {
            INSERT(u0, j0); INSERT(u1, j1); INSERT(u2, j2); INSERT(u3, j3);
        }
    }

    if (part == 0) {
        const float e1 = expf(v1 - v0);
        const float e2 = expf(v2 - v0);
        const float e3 = expf(v3 - v0);
        const float s  = 1.0f + e1 + e2 + e3;
        float4 ov = {1.0f / s, e1 / s, e2 / s, e3 / s};
        float4 oi = {(float)i0, (float)i1, (float)i2, (float)i3};
        *reinterpret_cast<float4*>(&vals[(size_t)tok * 4]) = ov;
        *reinterpret_cast<float4*>(&inds[(size_t)tok * 4]) = oi;
    }
}

extern "C" void kernel_launch(void* const* d_in, const int* in_sizes, int n_in,
                              void* d_out, int out_size, void* d_ws, size_t ws_size,
                              hipStream_t stream) {
    const float* x    = (const float*)d_in[0];   // [16384,2880]
    const float* w    = (const float*)d_in[1];   // [128,2880]
    const float* bias = (const float*)d_in[2];   // [128]

    float* out    = (float*)d_out;
    float* vals   = out;                          // 16384*4
    float* inds   = out + NTOK * 4;               // 16384*4
    float* logits = out + NTOK * 8;               // 16384*128

    const size_t PBYTES = (size_t)NTOK * NEXP * sizeof(float);  // 8.39 MB per slice
    int ks = 1;
    if (ws_size >= 3 * PBYTES)      ks = 4;
    else if (ws_size >= PBYTES)     ks = 2;

    dim3 grid1(NTOK / BM, ks);                    // (256, ks)
    router_gemm<<<grid1, 256, 0, stream>>>(x, w, logits, (float*)d_ws);

    // 8 threads per token
    reduce_topk_softmax<<<(NTOK * 8) / 256, 256, 0, stream>>>(
        logits, (const float*)d_ws, bias, vals, inds, ks);
}

// Round 4
// 183.565 us; speedup vs baseline: 1.7880x; 1.7880x over previous
//
#include <hip/hip_runtime.h>
#include <math.h>

#define H      2880
#define H4     720
#define NTOK   16384
#define NEXP   128
#define KT     32          // K per chunk
#define NCHUNK 90
#define BM     128         // tokens per block = 4 waves x 32
#define LDSPAD 40          // shorts per expert row (32 data + 8 pad) -> 80B stride

typedef __attribute__((ext_vector_type(8)))  short bf16x8;
typedef __attribute__((ext_vector_type(16))) float f32x16;

union FragU { unsigned int u[4]; bf16x8 v; };

// hi split: top 16 bits of fp32 (truncation). lo = x - hi is EXACT in fp32;
// lo truncated again -> total dropped <= 2^-16 |x|.
__device__ inline bf16x8 pack_hi2(float4 a, float4 b) {
    const float f[8] = {a.x,a.y,a.z,a.w,b.x,b.y,b.z,b.w};
    FragU r;
#pragma unroll
    for (int j = 0; j < 4; ++j) {
        unsigned u0 = __float_as_uint(f[2*j]);
        unsigned u1 = __float_as_uint(f[2*j+1]);
        r.u[j] = (u1 & 0xFFFF0000u) | (u0 >> 16);
    }
    return r.v;
}
__device__ inline bf16x8 pack_lo2(float4 a, float4 b) {
    const float f[8] = {a.x,a.y,a.z,a.w,b.x,b.y,b.z,b.w};
    FragU r;
#pragma unroll
    for (int j = 0; j < 4; ++j) {
        float x0 = f[2*j],   h0 = __uint_as_float(__float_as_uint(x0) & 0xFFFF0000u);
        float x1 = f[2*j+1], h1 = __uint_as_float(__float_as_uint(x1) & 0xFFFF0000u);
        unsigned l0 = __float_as_uint(x0 - h0);
        unsigned l1 = __float_as_uint(x1 - h1);
        r.u[j] = (l1 & 0xFFFF0000u) | (l0 >> 16);
    }
    return r.v;
}

// ---------------- Kernel 1: MFMA router GEMM (bf16 hi/lo x3 products), split-K ----------------
// approx logits, err ~3e-5. z=0 -> p0 (logits region), z>=1 -> pws slices.
__global__ __launch_bounds__(256) void router_gemm_mfma(
    const float* __restrict__ x,      // [NTOK][H]
    const float* __restrict__ w,      // [NEXP][H]
    float* __restrict__ p0,
    float* __restrict__ pws)
{
    __shared__ short bhi[2][NEXP * LDSPAD];   // 20480 B
    __shared__ short blo[2][NEXP * LDSPAD];   // 20480 B

    const int tid  = threadIdx.x;
    const int lane = tid & 63;
    const int wv   = tid >> 6;
    const int bm   = blockIdx.x;
    const int z    = blockIdx.y;
    const int ks   = gridDim.y;
    const int t0   = bm * BM;

    const int base = NCHUNK / ks, rem = NCHUNK % ks;
    const int c0 = z * base + (z < rem ? z : rem);
    const int c1 = c0 + base + (z < rem ? 1 : 0);

    float* outp = (z == 0) ? p0 : (pws + (size_t)(z - 1) * NTOK * NEXP);

    // B staging: thread t -> expert se = t>>1, k-seg sg = t&1 (16 fp32 -> 16 bf16 hi + 16 lo)
    const int se = tid >> 1;
    const int sg = tid & 1;
    const float4* wg = (const float4*)w;

    // A side: wave-private 32 tokens; lane -> row (lane&31), k-quarter (lane>>5)
    const int arow = t0 + wv * 32 + (lane & 31);
    const int akq  = lane >> 5;           // 0/1
    const float4* xg = (const float4*)x;

    f32x16 acc[4];
#pragma unroll
    for (int nt = 0; nt < 4; ++nt)
#pragma unroll
        for (int r = 0; r < 16; ++r) acc[nt][r] = 0.0f;

    float4 wa, wb, wc, wd;

#define WLOAD(c) {                                                             \
    const float4* wp = wg + (size_t)se * H4 + (c) * 8 + sg * 4;                \
    wa = wp[0]; wb = wp[1]; wc = wp[2]; wd = wp[3]; }

#define WSTORE(b) {                                                            \
    short* dh = &bhi[b][se * LDSPAD + sg * 16];                                \
    short* dl = &blo[b][se * LDSPAD + sg * 16];                                \
    *(bf16x8*)(dh)     = pack_hi2(wa, wb);                                     \
    *(bf16x8*)(dh + 8) = pack_hi2(wc, wd);                                     \
    *(bf16x8*)(dl)     = pack_lo2(wa, wb);                                     \
    *(bf16x8*)(dl + 8) = pack_lo2(wc, wd); }

    WLOAD(c0);
    WSTORE(0);
    __syncthreads();

    int cur = 0;
    for (int c = c0; c < c1; ++c) {
        const bool more = (c + 1 < c1);
        if (more) WLOAD(c + 1);

        // A: 16 fp32 of this chunk (2 k-halves x 8), direct from global
        const float4* xp = xg + (size_t)arow * H4 + c * 8 + akq * 2;
        float4 x0 = xp[0], x1 = xp[1];          // half h=0: k = akq*8 + 0..7
        float4 x2 = xp[4], x3 = xp[5];          // half h=1: +16 floats
        bf16x8 ah0 = pack_hi2(x0, x1), al0 = pack_lo2(x0, x1);
        bf16x8 ah1 = pack_hi2(x2, x3), al1 = pack_lo2(x2, x3);

#pragma unroll
        for (int nt = 0; nt < 4; ++nt) {
            const short* bp = &bhi[cur][(nt * 32 + (lane & 31)) * LDSPAD];
            const short* lp = &blo[cur][(nt * 32 + (lane & 31)) * LDSPAD];
            bf16x8 bh0 = *(const bf16x8*)(bp + akq * 8);
            bf16x8 bl0 = *(const bf16x8*)(lp + akq * 8);
            bf16x8 bh1 = *(const bf16x8*)(bp + 16 + akq * 8);
            bf16x8 bl1 = *(const bf16x8*)(lp + 16 + akq * 8);
            acc[nt] = __builtin_amdgcn_mfma_f32_32x32x16_bf16(ah0, bh0, acc[nt], 0, 0, 0);
            acc[nt] = __builtin_amdgcn_mfma_f32_32x32x16_bf16(al0, bh0, acc[nt], 0, 0, 0);
            acc[nt] = __builtin_amdgcn_mfma_f32_32x32x16_bf16(ah0, bl0, acc[nt], 0, 0, 0);
            acc[nt] = __builtin_amdgcn_mfma_f32_32x32x16_bf16(ah1, bh1, acc[nt], 0, 0, 0);
            acc[nt] = __builtin_amdgcn_mfma_f32_32x32x16_bf16(al1, bh1, acc[nt], 0, 0, 0);
            acc[nt] = __builtin_amdgcn_mfma_f32_32x32x16_bf16(ah1, bl1, acc[nt], 0, 0, 0);
        }

        if (more) WSTORE(cur ^ 1);   // writes other buffer; reads this iter were from cur
        __syncthreads();
        cur ^= 1;
    }

    // epilogue: D layout (32x32): col = lane&31, row = (r&3) + 8*(r>>2) + 4*(lane>>5)
    const int ecol  = lane & 31;
    const int rbase = t0 + wv * 32 + 4 * (lane >> 5);
#pragma unroll
    for (int nt = 0; nt < 4; ++nt)
#pragma unroll
        for (int r = 0; r < 16; ++r) {
            const int row = rbase + (r & 3) + 8 * (r >> 2);
            outp[(size_t)row * NEXP + nt * 32 + ecol] = acc[nt][r];
        }
}

// ---------------- Kernel 2: reduce slices + bias -> logits; approx top-8 candidates ----------
__global__ __launch_bounds__(64) void reduce_cand(
    float* __restrict__ p0,            // partial 0 -> overwritten with final logits
    const float* __restrict__ pws,
    const float* __restrict__ bias,
    float* __restrict__ cand,          // [NTOK][8] candidate expert ids (as float)
    int ks)
{
    const int tok = blockIdx.x * 64 + threadIdx.x;
    float4* row = (float4*)p0 + (size_t)tok * 32;
    const float4* b4 = (const float4*)bias;

    float v[8]; int ix[8];
#pragma unroll
    for (int r = 0; r < 8; ++r) { v[r] = -3.4e38f; ix[r] = 0; }
    float vmin = -3.4e38f; int amin = 0;

    for (int g = 0; g < 32; ++g) {
        float4 s = row[g];
        for (int zz = 1; zz < ks; ++zz) {
            const float4 pz = ((const float4*)(pws + (size_t)(zz - 1) * NTOK * NEXP))[(size_t)tok * 32 + g];
            s.x += pz.x; s.y += pz.y; s.z += pz.z; s.w += pz.w;
        }
        const float4 bb = b4[g];
        s.x += bb.x; s.y += bb.y; s.z += bb.z; s.w += bb.w;
        row[g] = s;                                   // final (approx) logits

        const float q[4] = {s.x, s.y, s.z, s.w};
#pragma unroll
        for (int j = 0; j < 4; ++j) {
            const float val = q[j];
            const int   e   = g * 4 + j;
            if (val > vmin) {                         // unordered top-8: replace current min
#pragma unroll
                for (int r = 0; r < 8; ++r) if (r == amin) { v[r] = val; ix[r] = e; }
                vmin = v[0]; amin = 0;
#pragma unroll
                for (int r = 1; r < 8; ++r) if (v[r] < vmin) { vmin = v[r]; amin = r; }
            }
        }
    }
#pragma unroll
    for (int r = 0; r < 8; ++r) cand[(size_t)tok * 8 + r] = (float)ix[r];
}

// ---------------- Kernel 3: exact fp64 recompute of 8 candidates; rank; softmax --------------
__global__ __launch_bounds__(256) void fixup_topk(
    const float* __restrict__ x,
    const float* __restrict__ w,
    const float* __restrict__ bias,
    const float* __restrict__ cand,
    float* __restrict__ vals,
    float* __restrict__ inds)
{
    const int lane = threadIdx.x & 63;
    const int wv   = threadIdx.x >> 6;
    const int tok  = blockIdx.x * 4 + wv;
    const int c    = lane >> 3;       // candidate slot 0..7
    const int s    = lane & 7;        // k-segment
    const int cidx = (int)cand[(size_t)tok * 8 + c];

    const float4* xr = (const float4*)x + (size_t)tok  * H4;
    const float4* wr = (const float4*)w + (size_t)cidx * H4;

    double acc = 0.0;
    for (int j = 0; j < 90; ++j) {
        const float4 a = xr[s + 8 * j];
        const float4 b = wr[s + 8 * j];
        acc = fma((double)a.x, (double)b.x, acc);
        acc = fma((double)a.y, (double)b.y, acc);
        acc = fma((double)a.z, (double)b.z, acc);
        acc = fma((double)a.w, (double)b.w, acc);
    }
    acc += __shfl_xor(acc, 1);
    acc += __shfl_xor(acc, 2);
    acc += __shfl_xor(acc, 4);
    const double exact = acc + (double)bias[cidx];    // all 8 lanes of group hold it

    double bv[8]; int bidx[8];
#pragma unroll
    for (int g = 0; g < 8; ++g) { bv[g] = __shfl(exact, g * 8); bidx[g] = __shfl(cidx, g * 8); }

    // exact top-4 with lax.top_k tie rule (lower expert index wins ties)
    float fv[4]; int fi[4];
#pragma unroll
    for (int k = 0; k < 4; ++k) {
        double best = -1.0e300; int bi = 1 << 30; int bg = -1;
#pragma unroll
        for (int g = 0; g < 8; ++g) {
            if (bv[g] > best || (bv[g] == best && bidx[g] < bi)) { best = bv[g]; bi = bidx[g]; bg = g; }
        }
#pragma unroll
        for (int g = 0; g < 8; ++g) if (g == bg) bv[g] = -1.0e300;
        fv[k] = (float)best; fi[k] = bi;
    }

    if (lane == 0) {
        const float e1 = expf(fv[1] - fv[0]);
        const float e2 = expf(fv[2] - fv[0]);
        const float e3 = expf(fv[3] - fv[0]);
        const float sm = 1.0f + e1 + e2 + e3;
        float4 ov = {1.0f / sm, e1 / sm, e2 / sm, e3 / sm};
        float4 oi = {(float)fi[0], (float)fi[1], (float)fi[2], (float)fi[3]};
        *(float4*)(&vals[(size_t)tok * 4]) = ov;
        *(float4*)(&inds[(size_t)tok * 4]) = oi;
    }
}

extern "C" void kernel_launch(void* const* d_in, const int* in_sizes, int n_in,
                              void* d_out, int out_size, void* d_ws, size_t ws_size,
                              hipStream_t stream) {
    const float* x    = (const float*)d_in[0];
    const float* w    = (const float*)d_in[1];
    const float* bias = (const float*)d_in[2];

    float* out    = (float*)d_out;
    float* vals   = out;                 // 16384*4
    float* inds   = out + NTOK * 4;      // 16384*4
    float* logits = out + NTOK * 8;      // 16384*128

    const size_t PB = (size_t)NTOK * NEXP * sizeof(float);   // 8.39 MB
    const size_t CB = (size_t)NTOK * 8 * sizeof(float);      // 512 KB candidates
    int ks = 1;
    if      (ws_size >= 3 * PB + CB) ks = 4;
    else if (ws_size >= 2 * PB + CB) ks = 3;
    else if (ws_size >= 1 * PB + CB) ks = 2;

    float* pws  = (float*)d_ws;
    float* cand = (float*)d_ws + (size_t)(ks - 1) * NTOK * NEXP;

    router_gemm_mfma<<<dim3(NTOK / BM, ks), 256, 0, stream>>>(x, w, logits, pws);
    reduce_cand<<<NTOK / 64, 64, 0, stream>>>(logits, pws, bias, cand, ks);
    fixup_topk<<<NTOK / 4, 256, 0, stream>>>(x, w, bias, cand, vals, inds);
}